// Round 1
// baseline (897.777 us; speedup 1.0000x reference)
//
#include <hip/hip_runtime.h>
#include <stdint.h>

#define HIDN 128
#define EMBN 32

// ---------- helpers ----------
__device__ __forceinline__ unsigned bf16r(float f) {   // fp32 -> bf16 bits, RNE
  unsigned u = __float_as_uint(f);
  return (u + 0x7FFFu + ((u >> 16) & 1u)) >> 16;
}
__device__ __forceinline__ unsigned pack2(float a, float b) {  // a -> low 16, b -> high 16
  return bf16r(a) | (bf16r(b) << 16);
}
__device__ __forceinline__ float dp2(unsigned qu, unsigned ku, float acc) {
  float q0 = __uint_as_float(qu << 16);
  float q1 = __uint_as_float(qu & 0xFFFF0000u);
  float k0 = __uint_as_float(ku << 16);
  float k1 = __uint_as_float(ku & 0xFFFF0000u);
  return fmaf(q1, k1, fmaf(q0, k0, acc));
}
// monotone float<->uint encoding for atomicMax/Min. init max with 0x00, min with 0xFF.
__device__ __forceinline__ unsigned ford(float f) {
  unsigned u = __float_as_uint(f);
  return (u & 0x80000000u) ? ~u : (u | 0x80000000u);
}
__device__ __forceinline__ float oford(unsigned u) {
  return __uint_as_float((u & 0x80000000u) ? (u ^ 0x80000000u) : ~u);
}

// ---------- prep: fold W2 into Wq/Wk, build vsum weights, part-3 scalars ----------
__global__ __launch_bounds__(256) void k_prep(
    const float* __restrict__ W2, const float* __restrict__ b2,
    const float* __restrict__ Wq, const float* __restrict__ Wk, const float* __restrict__ Wv,
    const float* __restrict__ Wq2, const float* __restrict__ Wk2, const float* __restrict__ Wv2,
    float* __restrict__ Wqp, float* __restrict__ bqp,
    float* __restrict__ Wkp, float* __restrict__ bkp,
    float* __restrict__ Wvsp, float* __restrict__ bvs,
    float* __restrict__ dhd, float* __restrict__ wv2s)
{
  __shared__ float wvs[HIDN * 4];   // wvs[l][h] = sum_dh Wv[l][h*32+dh]
  int t = threadIdx.x;
  for (int idx = t; idx < HIDN * 4; idx += 256) {
    int l = idx >> 2, h = idx & 3;
    float s = 0.f;
    for (int dh = 0; dh < 32; dh++) s += Wv[l * HIDN + h * 32 + dh];
    wvs[idx] = s;
  }
  __syncthreads();
  // Wq' = W2 @ Wq, Wk' = W2 @ Wk  [32][128]
  for (int idx = t; idx < EMBN * HIDN; idx += 256) {
    int i = idx >> 7, j = idx & 127;
    float aq = 0.f, ak = 0.f;
    for (int l = 0; l < HIDN; l++) {
      float w2 = W2[i * HIDN + l];
      aq = fmaf(w2, Wq[l * HIDN + j], aq);
      ak = fmaf(w2, Wk[l * HIDN + j], ak);
    }
    Wqp[idx] = aq; Wkp[idx] = ak;
  }
  // bq' = b2 @ Wq, bk' = b2 @ Wk
  for (int j = t; j < HIDN; j += 256) {
    float aq = 0.f, ak = 0.f;
    for (int l = 0; l < HIDN; l++) {
      float bb = b2[l];
      aq = fmaf(bb, Wq[l * HIDN + j], aq);
      ak = fmaf(bb, Wk[l * HIDN + j], ak);
    }
    bqp[j] = aq; bkp[j] = ak;
  }
  // WvS'[i][h] = sum_l W2[i][l]*wvs[l][h]
  for (int idx = t; idx < EMBN * 4; idx += 256) {
    int i = idx >> 2, h = idx & 3;
    float a = 0.f;
    for (int l = 0; l < HIDN; l++) a = fmaf(W2[i * HIDN + l], wvs[l * 4 + h], a);
    Wvsp[idx] = a;
  }
  if (t < 4) {
    float a = 0.f;
    for (int l = 0; l < HIDN; l++) a = fmaf(b2[l], wvs[l * 4 + t], a);
    bvs[t] = a;
    float d = 0.f, w = 0.f;
    for (int dh = 0; dh < 32; dh++) {
      d = fmaf(Wq2[t * 32 + dh], Wk2[t * 32 + dh], d);
      w += Wv2[t * 32 + dh];
    }
    dhd[t]  = d * 0.17677669529663687f;   // includes 1/sqrt(32)
    wv2s[t] = w;
  }
}

// ---------- K1: per-edge emb -> q,k (bf16), vsum ----------
__global__ __launch_bounds__(256) void k_edge(
    const float* __restrict__ x, const int* __restrict__ eidx, const float* __restrict__ ea,
    const float* __restrict__ W1, const float* __restrict__ b1,
    const float* __restrict__ Wqp, const float* __restrict__ bqp,
    const float* __restrict__ Wkp, const float* __restrict__ bkp,
    const float* __restrict__ Wvsp, const float* __restrict__ bvs,
    unsigned* __restrict__ qbf, unsigned* __restrict__ kbf,
    float* __restrict__ vsum, int E)
{
  int e = blockIdx.x * 256 + threadIdx.x;
  if (e >= E) return;
  int si = eidx[e], di = eidx[E + e];
  float xs = x[si], xd = x[di];

  float emb[EMBN];
#pragma unroll
  for (int i = 0; i < EMBN; i++)
    emb[i] = fmaf(xd, W1[EMBN + i], fmaf(xs, W1[i], b1[i]));

  const float4* ea4 = (const float4*)(ea + (size_t)e * 32);
#pragma unroll 1
  for (int rb = 0; rb < 8; rb++) {
    float4 v = ea4[rb];
    const float* w = W1 + (2 + rb * 4) * EMBN;
#pragma unroll
    for (int i = 0; i < EMBN; i++) emb[i] = fmaf(v.x, w[i], emb[i]);
#pragma unroll
    for (int i = 0; i < EMBN; i++) emb[i] = fmaf(v.y, w[EMBN + i], emb[i]);
#pragma unroll
    for (int i = 0; i < EMBN; i++) emb[i] = fmaf(v.z, w[2 * EMBN + i], emb[i]);
#pragma unroll
    for (int i = 0; i < EMBN; i++) emb[i] = fmaf(v.w, w[3 * EMBN + i], emb[i]);
  }
#pragma unroll
  for (int i = 0; i < EMBN; i++) emb[i] = fmaxf(emb[i], 0.f);

  unsigned* qrow = qbf + (size_t)e * 64;
  unsigned* krow = kbf + (size_t)e * 64;
#pragma unroll 1
  for (int jb = 0; jb < 16; jb++) {
    float qa[8], ka[8];
#pragma unroll
    for (int jj = 0; jj < 8; jj++) { qa[jj] = bqp[jb * 8 + jj]; ka[jj] = bkp[jb * 8 + jj]; }
#pragma unroll
    for (int i = 0; i < EMBN; i++) {
      float ev = emb[i];
      const float* wq = Wqp + i * HIDN + jb * 8;
      const float* wk = Wkp + i * HIDN + jb * 8;
#pragma unroll
      for (int jj = 0; jj < 8; jj++) qa[jj] = fmaf(ev, wq[jj], qa[jj]);
#pragma unroll
      for (int jj = 0; jj < 8; jj++) ka[jj] = fmaf(ev, wk[jj], ka[jj]);
    }
    uint4 qo, ko;
    qo.x = pack2(qa[0], qa[1]); qo.y = pack2(qa[2], qa[3]);
    qo.z = pack2(qa[4], qa[5]); qo.w = pack2(qa[6], qa[7]);
    ko.x = pack2(ka[0], ka[1]); ko.y = pack2(ka[2], ka[3]);
    ko.z = pack2(ka[4], ka[5]); ko.w = pack2(ka[6], ka[7]);
    ((uint4*)qrow)[jb] = qo;
    ((uint4*)krow)[jb] = ko;
  }

  float vs[4];
#pragma unroll
  for (int h = 0; h < 4; h++) vs[h] = bvs[h];
#pragma unroll
  for (int i = 0; i < EMBN; i++) {
    float ev = emb[i];
#pragma unroll
    for (int h = 0; h < 4; h++) vs[h] = fmaf(ev, Wvsp[i * 4 + h], vs[h]);
  }
  *(float4*)(vsum + (size_t)e * 4) = make_float4(vs[0], vs[1], vs[2], vs[3]);
}

// ---------- K3: line-graph attention pairs (no-max softmax, fused) ----------
__global__ __launch_bounds__(256) void k_pairs(
    const int* __restrict__ e2e, const unsigned* __restrict__ qbf,
    const unsigned* __restrict__ kbf, const float* __restrict__ vsum,
    float* __restrict__ s_acc, float* __restrict__ num_acc, int EE)
{
  int tid = blockIdx.x * 256 + threadIdx.x;
  int p = tid >> 2;
  if (p >= EE) return;
  int h = tid & 3;
  int es = e2e[p], ed = e2e[EE + p];
  const uint4* qp = (const uint4*)(qbf + (size_t)ed * 64 + h * 16);
  const uint4* kp = (const uint4*)(kbf + (size_t)es * 64 + h * 16);
  float dot = 0.f;
#pragma unroll
  for (int t4 = 0; t4 < 4; t4++) {
    uint4 qa = qp[t4], ka = kp[t4];
    dot = dp2(qa.x, ka.x, dot);
    dot = dp2(qa.y, ka.y, dot);
    dot = dp2(qa.z, ka.z, dot);
    dot = dp2(qa.w, ka.w, dot);
  }
  float ev = __expf(dot * 0.17677669529663687f);   // 1/sqrt(32)
  atomicAdd(&s_acc[(size_t)ed * 4 + h], ev);
  atomicAdd(&num_acc[(size_t)ed * 4 + h], ev * vsum[(size_t)es * 4 + h]);
}

// ---------- K4: updated_edge_feat ----------
__global__ __launch_bounds__(256) void k_uef(
    const float* __restrict__ s_acc, const float* __restrict__ num_acc,
    float* __restrict__ out1, int E)
{
  int e = blockIdx.x * 256 + threadIdx.x;
  if (e >= E) return;
  float acc = 0.f;
#pragma unroll
  for (int h = 0; h < 4; h++)
    acc += num_acc[(size_t)e * 4 + h] / (s_acc[(size_t)e * 4 + h] + 1e-16f);
  out1[e] = acc * 0.0078125f;   // 1/128
}

// ---------- K5: part-3 pass A: a_c, segment max/min ----------
__global__ __launch_bounds__(256) void k_n2n_a(
    const int* __restrict__ n2n, const float* __restrict__ x, const float* __restrict__ out,
    int C, int N, float* __restrict__ a_ws, float* __restrict__ as_ws,
    unsigned* __restrict__ amax_u, unsigned* __restrict__ amin_u)
{
  int c = blockIdx.x * 256 + threadIdx.x;
  if (c >= C) return;
  int ns = n2n[c], nd = n2n[C + c];
  float an  = (nd < N) ? x[nd] : out[nd];   // nef: idx>=N aliases d_out[idx] (uef)
  float asv = (ns < N) ? x[ns] : out[ns];
  float a = an * asv;
  a_ws[c] = a; as_ws[c] = asv;
  if (nd < N) {                              // nd>=N segments are dropped by the reference
    unsigned enc = ford(a);
    atomicMax(&amax_u[nd], enc);
    atomicMin(&amin_u[nd], enc);
  }
}

// ---------- K6: part-3 pass B: exp + accumulate ----------
__global__ __launch_bounds__(256) void k_n2n_b(
    const int* __restrict__ n2n, const float* __restrict__ a_ws, const float* __restrict__ as_ws,
    const unsigned* __restrict__ amax_u, const unsigned* __restrict__ amin_u,
    const float* __restrict__ dhd, float* __restrict__ s2, float* __restrict__ t2,
    int C, int N)
{
  int c = blockIdx.x * 256 + threadIdx.x;
  if (c >= C) return;
  int nd = n2n[C + c];
  if (nd >= N) return;
  float a = a_ws[c], asv = as_ws[c];
  float amx = oford(amax_u[nd]), amn = oford(amin_u[nd]);
#pragma unroll
  for (int h = 0; h < 4; h++) {
    float d = dhd[h];
    float m = (d > 0.f) ? d * amx : d * amn;
    float ev = __expf(fmaf(a, d, -m));       // <= 1, exact max-subtracted semantics
    atomicAdd(&s2[(size_t)nd * 4 + h], ev);
    atomicAdd(&t2[(size_t)nd * 4 + h], ev * asv);
  }
}

// ---------- K7: aggregated_node_feat ----------
__global__ __launch_bounds__(256) void k_final(
    const float* __restrict__ s2, const float* __restrict__ t2,
    const float* __restrict__ wv2s, float* __restrict__ out0, int N)
{
  int j = blockIdx.x * 256 + threadIdx.x;
  if (j >= N) return;
  float acc = 0.f;
#pragma unroll
  for (int h = 0; h < 4; h++)
    acc += wv2s[h] * t2[(size_t)j * 4 + h] / (s2[(size_t)j * 4 + h] + 1e-16f);
  out0[j] = acc * 0.0078125f;   // 1/128
}

extern "C" void kernel_launch(void* const* d_in, const int* in_sizes, int n_in,
                              void* d_out, int out_size, void* d_ws, size_t ws_size,
                              hipStream_t stream)
{
  const float* x   = (const float*)d_in[0];
  const int*   eidx= (const int*)d_in[1];
  const float* ea  = (const float*)d_in[2];
  const int*   e2e = (const int*)d_in[3];
  const int*   n2n = (const int*)d_in[4];
  const float* W1  = (const float*)d_in[5];
  const float* b1  = (const float*)d_in[6];
  const float* W2  = (const float*)d_in[7];
  const float* b2  = (const float*)d_in[8];
  const float* Wq  = (const float*)d_in[9];
  const float* Wk  = (const float*)d_in[10];
  const float* Wv  = (const float*)d_in[11];
  const float* Wq2 = (const float*)d_in[12];
  const float* Wk2 = (const float*)d_in[13];
  const float* Wv2 = (const float*)d_in[14];

  const int N  = in_sizes[0];        // x is [N,1]
  const int E  = in_sizes[1] / 2;
  const int EE = in_sizes[3] / 2;
  const int C  = in_sizes[4] / 2;

  float* out0 = (float*)d_out;       // [N]
  float* out1 = (float*)d_out + N;   // [E]

  char* w = (char*)d_ws;
  size_t off = 0;
  auto alloc = [&](size_t bytes) -> char* {
    char* p = w + off;
    off += (bytes + 255) & ~(size_t)255;
    return p;
  };
  float* Wqp   = (float*)alloc((size_t)EMBN * HIDN * 4);
  float* bqp   = (float*)alloc(HIDN * 4);
  float* Wkp   = (float*)alloc((size_t)EMBN * HIDN * 4);
  float* bkp   = (float*)alloc(HIDN * 4);
  float* Wvsp  = (float*)alloc(EMBN * 4 * 4);
  float* bvs   = (float*)alloc(16);
  float* dhd   = (float*)alloc(16);
  float* wv2s  = (float*)alloc(16);
  unsigned* qbf = (unsigned*)alloc((size_t)E * 64 * 4);   // bf16 q, 2/uint
  unsigned* kbf = (unsigned*)alloc((size_t)E * 64 * 4);   // bf16 k
  float* vsum  = (float*)alloc((size_t)E * 4 * 4);
  float* a_ws  = (float*)alloc((size_t)C * 4);
  float* as_ws = (float*)alloc((size_t)C * 4);
  char* zbase = w + off;                                   // --- zeroed block ---
  float* s_acc   = (float*)alloc((size_t)E * 4 * 4);
  float* num_acc = (float*)alloc((size_t)E * 4 * 4);
  float* s2      = (float*)alloc((size_t)N * 4 * 4);
  float* t2      = (float*)alloc((size_t)N * 4 * 4);
  unsigned* amax_u = (unsigned*)alloc((size_t)N * 4);
  size_t zbytes = (size_t)((w + off) - zbase);
  unsigned* amin_u = (unsigned*)alloc((size_t)N * 4);

  hipMemsetAsync(zbase, 0, zbytes, stream);
  hipMemsetAsync(amin_u, 0xFF, (size_t)N * 4, stream);

  k_prep<<<1, 256, 0, stream>>>(W2, b2, Wq, Wk, Wv, Wq2, Wk2, Wv2,
                                Wqp, bqp, Wkp, bkp, Wvsp, bvs, dhd, wv2s);
  k_edge<<<(E + 255) / 256, 256, 0, stream>>>(x, eidx, ea, W1, b1,
                                              Wqp, bqp, Wkp, bkp, Wvsp, bvs,
                                              qbf, kbf, vsum, E);
  k_pairs<<<(EE * 4 + 255) / 256, 256, 0, stream>>>(e2e, qbf, kbf, vsum, s_acc, num_acc, EE);
  k_uef<<<(E + 255) / 256, 256, 0, stream>>>(s_acc, num_acc, out1, E);
  k_n2n_a<<<(C + 255) / 256, 256, 0, stream>>>(n2n, x, (const float*)d_out, C, N,
                                               a_ws, as_ws, amax_u, amin_u);
  k_n2n_b<<<(C + 255) / 256, 256, 0, stream>>>(n2n, a_ws, as_ws, amax_u, amin_u, dhd,
                                               s2, t2, C, N);
  k_final<<<(N + 255) / 256, 256, 0, stream>>>(s2, t2, wv2s, out0, N);
}